// Round 9
// baseline (4925.090 us; speedup 1.0000x reference)
//
#include <hip/hip_runtime.h>
#include <cstdint>
#include <cstddef>

#define T_ 256
#define B_ 128
#define E_ 512
#define H_ 1024
#define BH (B_*H_)
#define GI (B_*3072)      // gi0 buffer (fp32): 128 x 3072
#define GATHER_BID 64     // barrier gatherer: an A-stage WG (has slack)

typedef _Float16 v8h __attribute__((ext_vector_type(8)));
typedef float    v4f __attribute__((ext_vector_type(4)));
typedef unsigned int u32x4 __attribute__((ext_vector_type(4)));

__device__ __forceinline__ float sigmoidf_(float x) {
    return 1.0f / (1.0f + __expf(-x));
}
__device__ __forceinline__ float tanhf_(float x) {
    return 1.0f - 2.0f / (__expf(2.0f * x) + 1.0f);
}

// Cross-WG mutable data: WRITTEN with L2-bypassing stores (lands in MALL),
// READ with normal cached loads after the barrier's acquire-inv.
__device__ __forceinline__ void sc_store2(void* p, unsigned v) {
    asm volatile("global_store_short %0, %1, off sc0 sc1" :: "v"(p), "v"(v) : "memory");
}
__device__ __forceinline__ void sc_store4(void* p, float v) {
    asm volatile("global_store_dword %0, %1, off sc0 sc1" :: "v"(p), "v"(v) : "memory");
}

// Non-draining chunk barrier: waits only LDS ops (lgkmcnt), NOT vmcnt —
// the 4-deep global prefetch queue stays in flight across it. This is the
// critical fix: __syncthreads emits s_waitcnt vmcnt(0) and was defeating
// the pipeline at every chunk (R7/R8: ~500cyc exposed latency x 48 chunks).
// The compiler still auto-inserts counted vmcnt(N) before each WRITEQ via
// the register dependency (loads complete in order).
#define LBAR() do { \
    asm volatile("s_waitcnt lgkmcnt(0)" ::: "memory"); \
    __builtin_amdgcn_s_barrier(); \
    asm volatile("" ::: "memory"); \
} while (0)

// ---------------------------------------------------------------------------
// Persistent 3-stage pipelined GRU (R8 structure; R9: non-draining barriers).
// Round k (k = 0..T+1):
//   D (bid 0..63):    gi0[t=k]   = x[t] @ Wi0.T   (k<=T-1); GEMM overlapped
//                     with the epoch wait (x immutable), store gated only.
//   A (bid 64..127):  h0/hn0[t=k-1] from gi0[t] + h0@Wh0, K=1024 (1<=k<=T)
//   B (bid 128..255): h1[t=k-2] full layer1 concat-K over
//                     [hn0[t] | h1[t-1]]; split n-gate accumulators.
// Weights in LDS per WG; fp32 h-masters in registers; flag/gatherer barrier.
// ---------------------------------------------------------------------------
__global__ __launch_bounds__(256, 1) void gru_persist(
    const int* __restrict__ bs,
    const _Float16* __restrict__ x16,   // [T][B][E]
    const _Float16* __restrict__ Wi0,   // [3072][512]
    const _Float16* __restrict__ Wh0,   // [3072][1024]
    const _Float16* __restrict__ Wi1,   // [3072][1024]
    const _Float16* __restrict__ Wh1,   // [3072][1024]
    const float* __restrict__ bias,     // [2][4][1024]
    float* __restrict__ h0f, float* __restrict__ h1f,       // fp32 out (final)
    _Float16* __restrict__ h0h, _Float16* __restrict__ h1h, // fp16 shadow x2
    _Float16* __restrict__ hn0,                             // layer0 out x2
    float* __restrict__ gi0,                                // fp32 x2
    int* __restrict__ flags,            // [256] per-WG round counters
    int* __restrict__ epoch)            // single epoch word
{
    __shared__ _Float16 WL[55296];          // 110,592 B weight slice
    __shared__ _Float16 AS[2][128][72];     //  36,864 B A-chunk dbuf

    const int bid = blockIdx.x;
    const int tid = threadIdx.x;
    const int lane = tid & 63, w = tid >> 6;
    const int m = lane & 15, q = lane >> 4;
    const int srow = tid >> 1, spart = tid & 1;
    const int stage = (bid < 64) ? 0 : (bid < 128) ? 1 : 2;
    const int sl = (stage == 0) ? bid : (stage == 1) ? bid - 64 : bid - 128;

    // ---- one-time: weight slice -> LDS ----
    if (stage == 0) {          // D: Wi0, 48 contiguous gate cols, 8 chunks
        for (int u = tid; u < 8 * 384; u += 256) {
            int kc = u / 384, rem = u % 384, c = rem >> 3, slot = rem & 7;
            int gr = sl * 48 + c;
            *(u32x4*)&WL[(kc * 48 + c) * 72 + slot * 8] =
                *(const u32x4*)(Wi0 + (size_t)gr * E_ + kc * 64 + slot * 8);
        }
    } else if (stage == 1) {   // A: Wh0, 48 cols grouped [r16|z16|n16], 16 chunks
        for (int u = tid; u < 16 * 384; u += 256) {
            int kc = u / 384, rem = u % 384, c = rem >> 3, slot = rem & 7;
            int gr = (c >> 4) * 1024 + sl * 16 + (c & 15);
            *(u32x4*)&WL[(kc * 48 + c) * 72 + slot * 8] =
                *(const u32x4*)(Wh0 + (size_t)gr * H_ + kc * 64 + slot * 8);
        }
    } else {                   // B: Wi1 (kc<16) ++ Wh1, 24 cols [r8|z8|n8], 32 chunks
        for (int u = tid; u < 32 * 192; u += 256) {
            int kc = u / 192, rem = u % 192, c = rem >> 3, slot = rem & 7;
            int gr = (c >> 3) * 1024 + sl * 8 + (c & 7);
            const _Float16* src = (kc < 16) ? (Wi1 + (size_t)gr * H_ + kc * 64)
                                            : (Wh1 + (size_t)gr * H_ + (kc - 16) * 64);
            *(u32x4*)&WL[(kc * 24 + c) * 72 + slot * 8] = *(const u32x4*)(src + slot * 8);
        }
    }
    __syncthreads();

    // ---- loop-invariant epilogue constants ----
    float br = 0.f, bz = 0.f, bi = 0.f, bh = 0.f;
    int colE = 0;                         // epilogue column
    if (stage == 1) {
        colE = sl * 16 + m;
        br = bias[colE]; bz = bias[H_ + colE];
        bi = bias[2 * H_ + colE]; bh = bias[3 * H_ + colE];
    } else if (stage == 2) {
        colE = sl * 8 + (m & 7);
        const float* bb = bias + 4 * H_;
        br = bb[colE]; bz = bb[H_ + colE];
        bi = bb[2 * H_ + colE]; bh = bb[3 * H_ + colE];
    }
    float hm[2][4];                       // register fp32 h-master (A/B)
#pragma unroll
    for (int rf = 0; rf < 2; ++rf)
#pragma unroll
        for (int r = 0; r < 4; ++r) hm[rf][r] = 0.f;

    v4f acc[6];
    u32x4 QA0, QA1, QA2, QA3, QB0, QB1, QB2, QB3;
    u32x4 QC0, QC1, QC2, QC3, QD0, QD1, QD2, QD3;

#define ISSUE(Qv, kcn) do { \
        const _Float16* p_ = sp + (size_t)(kcn) * 64; \
        Qv##0 = *(const u32x4*)(p_ + 0);  Qv##1 = *(const u32x4*)(p_ + 8); \
        Qv##2 = *(const u32x4*)(p_ + 16); Qv##3 = *(const u32x4*)(p_ + 24); \
    } while (0)
#define WRITEQ(Qv, dbuf) do { \
        _Float16* d_ = &AS[dbuf][srow][spart * 32]; \
        *(u32x4*)(d_ + 0) = Qv##0;  *(u32x4*)(d_ + 8)  = Qv##1; \
        *(u32x4*)(d_ + 16) = Qv##2; *(u32x4*)(d_ + 24) = Qv##3; \
    } while (0)
    // D/A: 3 col-frags of 16 (acc[cf*2+rf])
#define COMPUTE3(BUF, KC) do { \
        const _Float16* wch_ = &WL[(KC) * 48 * 72]; \
        _Pragma("unroll") \
        for (int s = 0; s < 2; ++s) { \
            const int ko = s * 32 + q * 8; \
            v8h a0 = *(const v8h*)&AS[BUF][32 * w + m][ko]; \
            v8h a1 = *(const v8h*)&AS[BUF][32 * w + 16 + m][ko]; \
            _Pragma("unroll") \
            for (int g = 0; g < 3; ++g) { \
                v8h b = *(const v8h*)&wch_[(g * 16 + m) * 72 + ko]; \
                acc[g * 2 + 0] = __builtin_amdgcn_mfma_f32_16x16x32_f16(a0, b, acc[g * 2 + 0], 0, 0, 0); \
                acc[g * 2 + 1] = __builtin_amdgcn_mfma_f32_16x16x32_f16(a1, b, acc[g * 2 + 1], 0, 0, 0); \
            } \
        } \
    } while (0)
#define CHUNK3(KC, QI, QW, BUF) do { \
        if ((KC) + 4 < nch) ISSUE(QI, (KC) + 4); \
        COMPUTE3(BUF, KC); \
        if ((KC) + 1 < nch) WRITEQ(QW, (BUF) ^ 1); \
        LBAR(); \
    } while (0)
    // B: cf0 = WL rows 0..15 [r|z], cf1 = rows 8..23 [z|n]
#define COMPUTE2(BUF, KC, ANB) do { \
        const _Float16* wch_ = &WL[(KC) * 24 * 72]; \
        _Pragma("unroll") \
        for (int s = 0; s < 2; ++s) { \
            const int ko = s * 32 + q * 8; \
            v8h a0 = *(const v8h*)&AS[BUF][32 * w + m][ko]; \
            v8h a1 = *(const v8h*)&AS[BUF][32 * w + 16 + m][ko]; \
            v8h b0 = *(const v8h*)&wch_[(m) * 72 + ko]; \
            v8h b1 = *(const v8h*)&wch_[(8 + m) * 72 + ko]; \
            acc[0] = __builtin_amdgcn_mfma_f32_16x16x32_f16(a0, b0, acc[0], 0, 0, 0); \
            acc[1] = __builtin_amdgcn_mfma_f32_16x16x32_f16(a1, b0, acc[1], 0, 0, 0); \
            acc[(ANB) + 0] = __builtin_amdgcn_mfma_f32_16x16x32_f16(a0, b1, acc[(ANB) + 0], 0, 0, 0); \
            acc[(ANB) + 1] = __builtin_amdgcn_mfma_f32_16x16x32_f16(a1, b1, acc[(ANB) + 1], 0, 0, 0); \
        } \
    } while (0)
#define SUBLOOP2(KB, ANB) do { \
        ISSUE(QA, 0); ISSUE(QB, 1); ISSUE(QC, 2); ISSUE(QD, 3); \
        WRITEQ(QA, 0); \
        LBAR(); \
        for (int base = 0; base < 16; base += 4) { \
            if (base + 4 < 16) ISSUE(QA, base + 4); \
            COMPUTE2(0, (KB) + base + 0, ANB); \
            if (base + 1 < 16) WRITEQ(QB, 1); \
            LBAR(); \
            if (base + 5 < 16) ISSUE(QB, base + 5); \
            COMPUTE2(1, (KB) + base + 1, ANB); \
            if (base + 2 < 16) WRITEQ(QC, 0); \
            LBAR(); \
            if (base + 6 < 16) ISSUE(QC, base + 6); \
            COMPUTE2(0, (KB) + base + 2, ANB); \
            if (base + 3 < 16) WRITEQ(QD, 1); \
            LBAR(); \
            if (base + 7 < 16) ISSUE(QD, base + 7); \
            COMPUTE2(1, (KB) + base + 3, ANB); \
            if (base + 4 < 16) WRITEQ(QA, 0); \
            LBAR(); \
        } \
    } while (0)

    // wait for epoch >= k; optional acquire-inv (L1/L2 invalidate)
#define WAIT_EPOCH(KV, DO_INV) do { \
        if (tid == 0) { \
            while (__hip_atomic_load(epoch, __ATOMIC_RELAXED, __HIP_MEMORY_SCOPE_AGENT) < (KV)) \
                __builtin_amdgcn_s_sleep(1); \
            if (DO_INV) (void)__hip_atomic_load(epoch, __ATOMIC_ACQUIRE, __HIP_MEMORY_SCOPE_AGENT); \
        } \
        __syncthreads(); \
    } while (0)
    // flag own round done; gatherer publishes epoch
#define DO_BARRIER(KV) do { \
        __syncthreads(); \
        if (tid == 0) \
            __hip_atomic_store(&flags[bid], (KV) + 1, __ATOMIC_RELEASE, __HIP_MEMORY_SCOPE_AGENT); \
        if (bid == GATHER_BID && tid < 64) { \
            const int tgt = (KV) + 1; \
            for (;;) { \
                int f0 = __hip_atomic_load(&flags[tid],       __ATOMIC_RELAXED, __HIP_MEMORY_SCOPE_AGENT); \
                int f1 = __hip_atomic_load(&flags[tid + 64],  __ATOMIC_RELAXED, __HIP_MEMORY_SCOPE_AGENT); \
                int f2 = __hip_atomic_load(&flags[tid + 128], __ATOMIC_RELAXED, __HIP_MEMORY_SCOPE_AGENT); \
                int f3 = __hip_atomic_load(&flags[tid + 192], __ATOMIC_RELAXED, __HIP_MEMORY_SCOPE_AGENT); \
                bool ok = (f0 >= tgt) && (f1 >= tgt) && (f2 >= tgt) && (f3 >= tgt); \
                if (__all(ok)) break; \
                __builtin_amdgcn_s_sleep(1); \
            } \
            if (tid == 0) \
                __hip_atomic_store(epoch, (KV) + 1, __ATOMIC_RELEASE, __HIP_MEMORY_SCOPE_AGENT); \
        } \
    } while (0)

    for (int k = 0; k < T_ + 2; ++k) {
        if (stage == 0) {
            // ================= D: gi0[t=k] = x[t] @ Wi0.T =================
            const bool active = (k < T_);
            if (active) {
                const int t = k;
#pragma unroll
                for (int i = 0; i < 6; ++i) acc[i] = (v4f){0.f, 0.f, 0.f, 0.f};
                const _Float16* sp = x16 + (size_t)t * B_ * E_ + (size_t)srow * E_ + spart * 32;
                const int nch = 8;
                ISSUE(QA, 0); ISSUE(QB, 1); ISSUE(QC, 2); ISSUE(QD, 3);
                WRITEQ(QA, 0);
                LBAR();
                CHUNK3(0, QA, QB, 0); CHUNK3(1, QB, QC, 1);
                CHUNK3(2, QC, QD, 0); CHUNK3(3, QD, QA, 1);
                CHUNK3(4, QA, QB, 0); CHUNK3(5, QB, QC, 1);
                CHUNK3(6, QC, QD, 0); CHUNK3(7, QD, QA, 1);
                // store gated by epoch only (ping-pong protection); no inv needed
                WAIT_EPOCH(k, false);
                float* gw = gi0 + (size_t)(t & 1) * GI;
                const int cbase = sl * 48;
#pragma unroll
                for (int cf = 0; cf < 3; ++cf)
#pragma unroll
                    for (int rf = 0; rf < 2; ++rf)
#pragma unroll
                        for (int r = 0; r < 4; ++r) {
                            int row = 32 * w + rf * 16 + q * 4 + r;
                            sc_store4(gw + (size_t)row * 3072 + cbase + cf * 16 + m,
                                      acc[cf * 2 + rf][r]);
                        }
            }
        } else if (stage == 1) {
            // ====== A: h0/hn0[t=k-1] from gi0[t] + h0[t-1]@Wh0 ======
            const bool active = (k >= 1) && (k <= T_);
            if (active) {
                const int t = k - 1;
                WAIT_EPOCH(k, true);
                const int bs_t = bs[t];
                const int pb = t & 1, rb = pb ^ 1;
#pragma unroll
                for (int i = 0; i < 6; ++i) acc[i] = (v4f){0.f, 0.f, 0.f, 0.f};
                const _Float16* sp = h0h + (size_t)rb * BH + (size_t)srow * H_ + spart * 32;
                const int nch = 16;
                ISSUE(QA, 0); ISSUE(QB, 1); ISSUE(QC, 2); ISSUE(QD, 3);
                WRITEQ(QA, 0);
                LBAR();
                for (int base = 0; base < 16; base += 4) {
                    CHUNK3(base + 0, QA, QB, 0); CHUNK3(base + 1, QB, QC, 1);
                    CHUNK3(base + 2, QC, QD, 0); CHUNK3(base + 3, QD, QA, 1);
                }
                // epilogue
                const float* gr_ = gi0 + (size_t)pb * GI;
                _Float16* hh_w = h0h + (size_t)pb * BH;
                _Float16* hn0w = hn0 + (size_t)pb * BH;
#pragma unroll
                for (int rf = 0; rf < 2; ++rf)
#pragma unroll
                    for (int r = 0; r < 4; ++r) {
                        int row = 32 * w + rf * 16 + q * 4 + r;
                        size_t go = (size_t)row * 3072 + colE;
                        float gir = gr_[go];
                        float giz = gr_[go + 1024];
                        float gin = gr_[go + 2048];
                        size_t off = (size_t)row * H_ + colE;
                        float hprev = hm[rf][r];
                        float rr = sigmoidf_(gir + acc[0 + rf][r] + br);
                        float zz = sigmoidf_(giz + acc[2 + rf][r] + bz);
                        float nn = tanhf_(gin + bi + rr * (acc[4 + rf][r] + bh));
                        float hnew = (1.0f - zz) * nn + zz * hprev;
                        bool act = row < bs_t;
                        float hsel = act ? hnew : hprev;
                        sc_store2(hn0w + off, (unsigned)__builtin_bit_cast(unsigned short, (_Float16)hnew));
                        sc_store2(hh_w + off, (unsigned)__builtin_bit_cast(unsigned short, (_Float16)hsel));
                        hm[rf][r] = hsel;
                    }
            } else if (bid == GATHER_BID) {
                WAIT_EPOCH(k, false);   // keep gatherer in step even when idle
            }
        } else {
            // ====== B: h1[t=k-2] = layer1(hn0[t], h1[t-1]); concat K=2048 ======
            const bool active = (k >= 2);
            if (active) {
                const int t = k - 2;
                WAIT_EPOCH(k, true);
                const int bs_t = bs[t];
                const int pb = t & 1, rb = pb ^ 1;
#pragma unroll
                for (int i = 0; i < 6; ++i) acc[i] = (v4f){0.f, 0.f, 0.f, 0.f};
                {   // sub-GEMM 1: hn0[t] @ Wi1 (WL chunks 0..15) -> accX = acc[2..3]
                    const _Float16* sp = hn0 + (size_t)pb * BH + (size_t)srow * H_ + spart * 32;
                    SUBLOOP2(0, 2);
                }
                {   // sub-GEMM 2: h1[t-1] @ Wh1 (WL chunks 16..31) -> accH = acc[4..5]
                    const _Float16* sp = h1h + (size_t)rb * BH + (size_t)srow * H_ + spart * 32;
                    SUBLOOP2(16, 4);
                }
                // epilogue: lane m<8 owns hidden col sl*8+m; z/in/hn via shfl(+8)
                _Float16* hh_w = h1h + (size_t)pb * BH;
#pragma unroll
                for (int rf = 0; rf < 2; ++rf)
#pragma unroll
                    for (int r = 0; r < 4; ++r) {
                        int row = 32 * w + rf * 16 + q * 4 + r;
                        float zz_s = __shfl_xor(acc[0 + rf][r], 8);
                        float inx  = __shfl_xor(acc[2 + rf][r], 8);
                        float hnh  = __shfl_xor(acc[4 + rf][r], 8);
                        float hprev = hm[rf][r];
                        float rr = sigmoidf_(acc[0 + rf][r] + br);
                        float zz = sigmoidf_(zz_s + bz);
                        float nn = tanhf_(inx + bi + rr * (hnh + bh));
                        float hnew = (1.0f - zz) * nn + zz * hprev;
                        bool act = row < bs_t;
                        float hsel = act ? hnew : hprev;
                        if (m < 8) {
                            size_t off = (size_t)row * H_ + colE;
                            sc_store2(hh_w + off, (unsigned)__builtin_bit_cast(unsigned short, (_Float16)hsel));
                        }
                        hm[rf][r] = hsel;
                    }
            }
        }

        // ---- barrier (skip after final round) ----
        if (k < T_ + 1) DO_BARRIER(k);
    }

    // ---- final fp32 writeback ----
    if (stage == 1) {
#pragma unroll
        for (int rf = 0; rf < 2; ++rf)
#pragma unroll
            for (int r = 0; r < 4; ++r) {
                int row = 32 * w + rf * 16 + q * 4 + r;
                h0f[(size_t)row * H_ + colE] = hm[rf][r];
            }
    } else if (stage == 2 && m < 8) {
#pragma unroll
        for (int rf = 0; rf < 2; ++rf)
#pragma unroll
            for (int r = 0; r < 4; ++r) {
                int row = 32 * w + rf * 16 + q * 4 + r;
                h1f[(size_t)row * H_ + colE] = hm[rf][r];
            }
    }
}

// ---------------------------------------------------------------------------
// Preamble / epilogue helpers
// ---------------------------------------------------------------------------
__global__ void cvt_f32_f16(const float* __restrict__ s, _Float16* __restrict__ d, int n) {
    int i = (blockIdx.x * 256 + threadIdx.x) * 8;
    if (i >= n) return;
    float4 v0 = *(const float4*)(s + i);
    float4 v1 = *(const float4*)(s + i + 4);
    v8h o = { (_Float16)v0.x, (_Float16)v0.y, (_Float16)v0.z, (_Float16)v0.w,
              (_Float16)v1.x, (_Float16)v1.y, (_Float16)v1.z, (_Float16)v1.w };
    *(v8h*)(d + i) = o;
}

__global__ void prep_bias(const float* __restrict__ bi0, const float* __restrict__ bh0,
                          const float* __restrict__ bi1, const float* __restrict__ bh1,
                          float* __restrict__ bias) {
    int tid = blockIdx.x * 256 + threadIdx.x;   // 2048 threads
    int l = tid >> 10, j = tid & 1023;
    const float* bi = l ? bi1 : bi0;
    const float* bh = l ? bh1 : bh0;
    float* o = bias + l * 4 * H_;
    o[j]           = bi[j] + bh[j];
    o[H_ + j]      = bi[H_ + j] + bh[H_ + j];
    o[2 * H_ + j]  = bi[2 * H_ + j];
    o[3 * H_ + j]  = bh[2 * H_ + j];
}

__global__ void gather_out(const float* __restrict__ h0f, const float* __restrict__ h1f,
                           const int* __restrict__ unsorted, float* __restrict__ out) {
    int rowid = blockIdx.x;          // 256 = L*B
    int l = rowid >> 7, b = rowid & 127;
    int src = unsorted[b];
    const float* s = (l ? h1f : h0f) + (size_t)src * H_;
    float* o = out + (size_t)rowid * H_;
    int c = threadIdx.x * 4;
    *(float4*)(o + c) = *(const float4*)(s + c);
}

// ---------------------------------------------------------------------------
extern "C" void kernel_launch(void* const* d_in, const int* in_sizes, int n_in,
                              void* d_out, int out_size, void* d_ws, size_t ws_size,
                              hipStream_t stream) {
    const float* x    = (const float*)d_in[0];
    const float* Wi0f = (const float*)d_in[1];
    const float* Wh0f = (const float*)d_in[2];
    const float* bi0  = (const float*)d_in[3];
    const float* bh0  = (const float*)d_in[4];
    const float* Wi1f = (const float*)d_in[5];
    const float* Wh1f = (const float*)d_in[6];
    const float* bi1  = (const float*)d_in[7];
    const float* bh1  = (const float*)d_in[8];
    const int*  bs       = (const int*)d_in[9];
    const int*  unsorted = (const int*)d_in[10];
    float* out = (float*)d_out;

    char* ws = (char*)d_ws;
    size_t off = 0;
    auto alloc = [&](size_t bytes) -> char* {
        char* p = ws + off;
        off += (bytes + 255) & ~(size_t)255;
        return p;
    };
    _Float16* x16 = (_Float16*)alloc((size_t)T_ * B_ * E_ * 2);
    _Float16* Wi0 = (_Float16*)alloc((size_t)3 * H_ * E_ * 2);
    _Float16* Wh0 = (_Float16*)alloc((size_t)3 * H_ * H_ * 2);
    _Float16* Wi1 = (_Float16*)alloc((size_t)3 * H_ * H_ * 2);
    _Float16* Wh1 = (_Float16*)alloc((size_t)3 * H_ * H_ * 2);
    float*    bias = (float*)alloc(2 * 4 * H_ * 4);
    float*    gi0  = (float*)alloc((size_t)2 * GI * 4);   // written before read
    float*    h0f  = (float*)alloc((size_t)BH * 4);       // written once at end
    float*    h1f  = (float*)alloc((size_t)BH * 4);
    char* zbase = ws + off;                  // zero-init block start
    _Float16* h0h = (_Float16*)alloc((size_t)2 * BH * 2);
    _Float16* h1h = (_Float16*)alloc((size_t)2 * BH * 2);
    _Float16* hn0 = (_Float16*)alloc((size_t)2 * BH * 2);
    int*      flags = (int*)alloc(1024);     // 256 flags
    int*      epoch = (int*)alloc(256);
    size_t zbytes = (size_t)((ws + off) - zbase);

    // fp16 shadows + flags/epoch must start at zero (h[-1] = 0, epoch 0).
    (void)hipMemsetAsync(zbase, 0, zbytes, stream);

    cvt_f32_f16<<<(T_ * B_ * E_) / 2048, 256, 0, stream>>>(x, x16, T_ * B_ * E_);
    cvt_f32_f16<<<(3 * H_ * E_) / 2048, 256, 0, stream>>>(Wi0f, Wi0, 3 * H_ * E_);
    cvt_f32_f16<<<(3 * H_ * H_) / 2048, 256, 0, stream>>>(Wh0f, Wh0, 3 * H_ * H_);
    cvt_f32_f16<<<(3 * H_ * H_) / 2048, 256, 0, stream>>>(Wi1f, Wi1, 3 * H_ * H_);
    cvt_f32_f16<<<(3 * H_ * H_) / 2048, 256, 0, stream>>>(Wh1f, Wh1, 3 * H_ * H_);
    prep_bias<<<8, 256, 0, stream>>>(bi0, bh0, bi1, bh1, bias);

    // Persistent: 256 WGs, 1/CU (147.5 KiB LDS), all co-resident.
    gru_persist<<<256, 256, 0, stream>>>(bs, x16, Wi0, Wh0, Wi1, Wh1, bias,
                                         h0f, h1f, h0h, h1h, hn0, gi0, flags, epoch);
    gather_out<<<256, 256, 0, stream>>>(h0f, h1f, unsorted, out);
}